// Round 8
// baseline (221.384 us; speedup 1.0000x reference)
//
#include <hip/hip_runtime.h>
#include <math.h>

#define IN_F 128
#define C1 32            // 2 heads * 16
#define NEG 0.2f
#define BSZ 256          // nodes per fine bucket (dst>>8)
#define CAP 4992         // edge-slot capacity per bucket (mean 4352, ~10 sigma)
#define EPB 2048         // edges per multisplit block

typedef _Float16 h16;
typedef _Float16 h16x2 __attribute__((ext_vector_type(2)));
typedef _Float16 h16x4 __attribute__((ext_vector_type(4)));

__device__ __forceinline__ float leaky(float x) { return x >= 0.f ? x : NEG * x; }

// ------- fat kernel: proj1 (blocks 0..nproj-1) | mscat (rest) -----------
// proj: 128 nodes/block, 4 nodes/thread; W in LDS (16KB), x from global
//       (L2-resident reuse). 8 LDS b128 per 64 FMA.
// mscat: LDS-histogram multisplit of edges into coarse dst-buckets.
__global__ __launch_bounds__(256)
void k_fat(const float* __restrict__ x, const float* __restrict__ W1,
           const float* __restrict__ a_s, const float* __restrict__ a_d,
           h16* __restrict__ h1h, float* __restrict__ as1,
           float* __restrict__ ad1, int N,
           const int* __restrict__ ei, int E, int ET, int nbk,
           int* __restrict__ bcnt, int* __restrict__ ebuf, int nproj) {
    __shared__ int smem[5120];                   // 20 KB union
    int t = threadIdx.x;
    if ((int)blockIdx.x < nproj) {
        // ---------------- projection branch ----------------
        float* Wl = (float*)smem;                // [k][32] = 16 KB
        for (int i = t; i < IN_F * C1 / 4; i += 256)
            ((float4*)Wl)[i] = ((const float4*)W1)[i];
        __syncthreads();
        int colq = t & 7, g = t >> 3;            // g 0..31
        int base = blockIdx.x * 128;
        const float4* wp = (const float4*)Wl;    // [k][8] float4
        int nn[4]; const float4* xp[4];
        #pragma unroll
        for (int j = 0; j < 4; ++j) {
            int node = base + g + 32 * j;
            nn[j] = node;
            int cl = node < N ? node : 0;
            xp[j] = (const float4*)(x + (size_t)cl * IN_F);
        }
        float4 acc[4];
        #pragma unroll
        for (int j = 0; j < 4; ++j) acc[j] = make_float4(0.f, 0.f, 0.f, 0.f);
        #pragma unroll 2
        for (int k4 = 0; k4 < IN_F / 4; ++k4) {
            float4 w0 = wp[(k4 * 4 + 0) * 8 + colq];
            float4 w1 = wp[(k4 * 4 + 1) * 8 + colq];
            float4 w2 = wp[(k4 * 4 + 2) * 8 + colq];
            float4 w3 = wp[(k4 * 4 + 3) * 8 + colq];
            #pragma unroll
            for (int j = 0; j < 4; ++j) {
                float4 xv = xp[j][k4];
                acc[j].x = fmaf(xv.x, w0.x, acc[j].x); acc[j].y = fmaf(xv.x, w0.y, acc[j].y);
                acc[j].z = fmaf(xv.x, w0.z, acc[j].z); acc[j].w = fmaf(xv.x, w0.w, acc[j].w);
                acc[j].x = fmaf(xv.y, w1.x, acc[j].x); acc[j].y = fmaf(xv.y, w1.y, acc[j].y);
                acc[j].z = fmaf(xv.y, w1.z, acc[j].z); acc[j].w = fmaf(xv.y, w1.w, acc[j].w);
                acc[j].x = fmaf(xv.z, w2.x, acc[j].x); acc[j].y = fmaf(xv.z, w2.y, acc[j].y);
                acc[j].z = fmaf(xv.z, w2.z, acc[j].z); acc[j].w = fmaf(xv.z, w2.w, acc[j].w);
                acc[j].x = fmaf(xv.w, w3.x, acc[j].x); acc[j].y = fmaf(xv.w, w3.y, acc[j].y);
                acc[j].z = fmaf(xv.w, w3.z, acc[j].z); acc[j].w = fmaf(xv.w, w3.w, acc[j].w);
            }
        }
        int cb = colq * 4;
        float as0 = a_s[cb], as1c = a_s[cb + 1], as2c = a_s[cb + 2], as3 = a_s[cb + 3];
        float ad0 = a_d[cb], ad1c = a_d[cb + 1], ad2c = a_d[cb + 2], ad3 = a_d[cb + 3];
        #pragma unroll
        for (int j = 0; j < 4; ++j) {
            bool vld = nn[j] < N;
            if (vld) {
                h16x4 hv = { (h16)acc[j].x, (h16)acc[j].y, (h16)acc[j].z, (h16)acc[j].w };
                *(h16x4*)(h1h + (size_t)nn[j] * C1 + cb) = hv;
            }
            float sv = acc[j].x * as0 + acc[j].y * as1c + acc[j].z * as2c + acc[j].w * as3;
            float dv = acc[j].x * ad0 + acc[j].y * ad1c + acc[j].z * ad2c + acc[j].w * ad3;
            sv += __shfl_xor(sv, 1); dv += __shfl_xor(dv, 1);
            sv += __shfl_xor(sv, 2); dv += __shfl_xor(dv, 2);
            if (vld && colq == 0) { as1[nn[j] * 2 + 0] = sv; ad1[nn[j] * 2 + 0] = dv; }
            if (vld && colq == 4) { as1[nn[j] * 2 + 1] = sv; ad1[nn[j] * 2 + 1] = dv; }
        }
    } else {
        // ---------------- multisplit branch ----------------
        int* hist = smem;                       // 512
        int* lcur = hist + 512;                 // 512
        int2* ecache = (int2*)(lcur + 512);     // EPB int2 = 16 KB
        int bid = blockIdx.x - nproj;
        hist[t] = 0; hist[t + 256] = 0;
        __syncthreads();
        int i0 = bid * EPB, i1 = min(ET, i0 + EPB);
        for (int i = i0 + t; i < i1; i += 256) {
            int s, d;
            if (i < E) { s = ei[i]; d = ei[E + i]; } else { s = d = i - E; }
            ecache[i - i0] = make_int2(s, d);
            atomicAdd(&hist[d >> 8], 1);
        }
        __syncthreads();
        for (int b = t; b < nbk; b += 256) {
            int h = hist[b];
            int base = h ? atomicAdd(&bcnt[b], h) : 0;
            lcur[b] = b * CAP + base;
        }
        __syncthreads();
        for (int i = i0 + t; i < i1; i += 256) {
            int2 e = ecache[i - i0];
            int bkt = e.y >> 8;
            int pos = atomicAdd(&lcur[bkt], 1);
            if (pos < (bkt + 1) * CAP)             // safety net vs overflow
                ebuf[pos] = (e.x << 8) | (e.y & 255);
        }
    }
}

// -------- per-bucket CSR build + fused attention weights ----------------
// fbase computed inline; final loop 4-batched for latency overlap.
__global__ __launch_bounds__(256)
void k_bcsr(const int* __restrict__ bcnt, const int* __restrict__ ebuf,
            int N, int nbk, int ET,
            const float* __restrict__ as1, const float* __restrict__ ad1,
            int* __restrict__ off, int2* __restrict__ csr2) {
    __shared__ int deg[256];
    __shared__ int cur[256];
    __shared__ float adl[512];           // ad1 window for this bucket
    __shared__ int red[4];
    int b = blockIdx.x, t = threadIdx.x;
    // fbase = sum_{k<b} min(bcnt[k], CAP)
    int part = 0;
    for (int k = t; k < b; k += 256) part += min(bcnt[k], CAP);
    part += __shfl_xor(part, 1);  part += __shfl_xor(part, 2);
    part += __shfl_xor(part, 4);  part += __shfl_xor(part, 8);
    part += __shfl_xor(part, 16); part += __shfl_xor(part, 32);
    if ((t & 63) == 0) red[t >> 6] = part;
    int cnt = min(bcnt[b], CAP);
    int ebase = b * CAP;
    int n0 = b * BSZ;
    deg[t] = 0;
    if (n0 + t < N) ((float2*)adl)[t] = ((const float2*)ad1)[n0 + t];
    __syncthreads();
    int fbase = red[0] + red[1] + red[2] + red[3];
    if (b == nbk - 1 && t == 0) off[N] = fbase + cnt;
    for (int i = t; i < cnt; i += 256)
        atomicAdd(&deg[ebuf[ebase + i] & 255], 1);
    __syncthreads();
    int v = deg[t];
    __syncthreads();
    for (int o = 1; o < 256; o <<= 1) {
        int xv = (t >= o) ? deg[t - o] : 0; __syncthreads();
        deg[t] += xv; __syncthreads();
    }
    int excl = deg[t] - v;
    if (n0 + t < N) off[n0 + t] = fbase + excl;
    cur[t] = fbase + excl;
    __syncthreads();
    const float2* as1v = (const float2*)as1;
    for (int i = t; i < cnt; i += 1024) {
        int e4[4]; float2 a4[4];
        #pragma unroll
        for (int k = 0; k < 4; ++k) {
            int idx = i + k * 256;
            bool vd = idx < cnt;
            int e = ebuf[ebase + (vd ? idx : 0)];
            e4[k] = vd ? e : -1;
            a4[k] = as1v[e >> 8];
        }
        #pragma unroll
        for (int k = 0; k < 4; ++k) {
            if (e4[k] < 0) continue;
            int dl = e4[k] & 255, s = e4[k] >> 8;
            float w0 = __expf(leaky(a4[k].x + adl[dl * 2 + 0]));
            float w1 = __expf(leaky(a4[k].y + adl[dl * 2 + 1]));
            h16x2 wpk = { (h16)w0, (h16)w1 };
            int p = atomicAdd(&cur[dl], 1);
            int2 rec; rec.x = s; rec.y = *(int*)&wpk;
            csr2[p] = rec;
        }
    }
}

// ---- layer-1: gather aggregation with precomputed weights --------------
__global__ __launch_bounds__(256)
void k_l1agg(const int* __restrict__ off, const int2* __restrict__ csr2,
             const h16* __restrict__ h1h, const float* __restrict__ b1,
             const float* __restrict__ W2, float* __restrict__ p2, int N) {
    int t = threadIdx.x;
    int node = blockIdx.x * 32 + (t >> 3);
    if (node >= N) return;
    int l = t & 7;
    int c0 = l * 4;                 // channels c0..c0+3 (head = l>>2)
    int head = l >> 2;
    float den = 0.f, a0 = 0.f, a1 = 0.f, a2 = 0.f, a3 = 0.f;
    int j0 = off[node], j1 = off[node + 1];   // j1 > j0 (self-loop guaranteed)
    for (int j = j0; j < j1; j += 4) {
        #pragma unroll
        for (int k = 0; k < 4; ++k) {
            int jj = j + k;
            bool valid = jj < j1;
            jj = valid ? jj : j0;             // safe clamp
            int2 e = csr2[jj];                // 8B broadcast
            int s = e.x;
            h16x2 wv = *(h16x2*)&e.y;
            float w = valid ? (float)(head ? wv.y : wv.x) : 0.f;
            h16x4 hv = *(const h16x4*)(h1h + ((size_t)s << 5) + c0);  // 8B gather
            den += w;
            a0 = fmaf(w, (float)hv.x, a0);
            a1 = fmaf(w, (float)hv.y, a1);
            a2 = fmaf(w, (float)hv.z, a2);
            a3 = fmaf(w, (float)hv.w, a3);
        }
    }
    float inv = 1.f / (den + 1e-16f);
    float o, val = 0.f;
    o = a0 * inv + b1[c0 + 0]; o = o > 0.f ? o : expm1f(o); val = fmaf(o, W2[c0 + 0], val);
    o = a1 * inv + b1[c0 + 1]; o = o > 0.f ? o : expm1f(o); val = fmaf(o, W2[c0 + 1], val);
    o = a2 * inv + b1[c0 + 2]; o = o > 0.f ? o : expm1f(o); val = fmaf(o, W2[c0 + 2], val);
    o = a3 * inv + b1[c0 + 3]; o = o > 0.f ? o : expm1f(o); val = fmaf(o, W2[c0 + 3], val);
    val += __shfl_xor(val, 1); val += __shfl_xor(val, 2); val += __shfl_xor(val, 4);
    if (l == 0) p2[node] = val;
}

// ---- layer-2: 4 lanes per node, 2-unroll (8 chains in flight) ----------
__global__ __launch_bounds__(256)
void k_l2(const int* __restrict__ off, const int2* __restrict__ csr2,
          const float* __restrict__ p2, const float* __restrict__ as2,
          const float* __restrict__ ad2, const float* __restrict__ b2,
          float* __restrict__ out, int N) {
    int t = threadIdx.x;
    int node = blockIdx.x * 64 + (t >> 2);
    if (node >= N) return;
    int l = t & 3;
    float A = as2[0];
    float Bc = ad2[0] * p2[node];
    float den = 0.f, num = 0.f;
    int j0 = off[node], j1 = off[node + 1];
    for (int j = j0 + l; j < j1; j += 8) {
        int s0 = csr2[j].x;
        int jb = j + 4;
        bool vb = jb < j1;
        int s1 = csr2[vb ? jb : j].x;
        float ps0 = p2[s0], ps1 = p2[s1];
        float w0 = __expf(leaky(fmaf(ps0, A, Bc)));
        float w1 = vb ? __expf(leaky(fmaf(ps1, A, Bc))) : 0.f;
        den += w0 + w1;
        num = fmaf(w0, ps0, fmaf(w1, ps1, num));
    }
    den += __shfl_xor(den, 1); den += __shfl_xor(den, 2);
    num += __shfl_xor(num, 1); num += __shfl_xor(num, 2);
    if (l == 0) out[node] = num / (den + 1e-16f) + b2[0];
}

extern "C" void kernel_launch(void* const* d_in, const int* in_sizes, int n_in,
                              void* d_out, int out_size, void* d_ws, size_t ws_size,
                              hipStream_t stream) {
    const float* x    = (const float*)d_in[0];
    const int*   ei   = (const int*)d_in[1];
    const float* W1   = (const float*)d_in[2];
    const float* a_s1 = (const float*)d_in[3];
    const float* a_d1 = (const float*)d_in[4];
    const float* b1   = (const float*)d_in[5];
    const float* W2   = (const float*)d_in[6];
    const float* a_s2 = (const float*)d_in[7];
    const float* a_d2 = (const float*)d_in[8];
    const float* b2   = (const float*)d_in[9];
    float* out = (float*)d_out;

    const int N  = in_sizes[0] / IN_F;   // 100000
    const int E  = in_sizes[1] / 2;      // 1600000
    const int ET = E + N;
    const int nbk = (N + BSZ - 1) / BSZ;              // 391 buckets

    // workspace layout (~30 MB; only bcnt needs zeroing)
    float* w   = (float*)d_ws;
    float* as1 = w; w += (size_t)2 * N;
    float* ad1 = w; w += (size_t)2 * N;
    float* p2  = w; w += (size_t)N;
    h16* h1h   = (h16*)w;                // 32*N halves = 16*N floats
    w += (size_t)16 * N;
    int* iw     = (int*)w;
    int* bcnt   = iw; iw += 512;
    int* off    = iw; iw += (N + 1);
    iw += (iw - (int*)d_ws) & 1;         // 8B-align csr2
    int2* csr2  = (int2*)iw; iw += (size_t)2 * ET;
    int* ebuf   = iw; iw += (size_t)nbk * CAP;

    const int B = 256;
    const int nproj = (N + 127) / 128;                // 782 proj blocks
    const int nblkA = (ET + EPB - 1) / EPB;           // 831 multisplit blocks

    hipMemsetAsync(bcnt, 0, 512 * sizeof(int), stream);
    k_fat  <<<nproj + nblkA, B, 0, stream>>>(x, W1, a_s1, a_d1, h1h, as1, ad1, N,
                                             ei, E, ET, nbk, bcnt, ebuf, nproj);
    k_bcsr <<<nbk, B, 0, stream>>>(bcnt, ebuf, N, nbk, ET, as1, ad1, off, csr2);
    k_l1agg<<<(N + 31) / 32, B, 0, stream>>>(off, csr2, h1h, b1, W2, p2, N);
    k_l2   <<<(N + 63) / 64, B, 0, stream>>>(off, csr2, p2, a_s2, a_d2, b2, out, N);
}